// Round 1
// baseline (138.144 us; speedup 1.0000x reference)
//
#include <hip/hip_runtime.h>

#define AMBIENT 0.6f
#define DIFFUSE 0.8f

// Kernel 1: precompute shaded[P,3] = clip(features * (AMBIENT + DIFFUSE*|n.l|), 0, 1)
__global__ void shade_kernel(const float* __restrict__ features,
                             const float* __restrict__ normals,
                             const float* __restrict__ light_dir,
                             float* __restrict__ shaded, int P) {
    int p = blockIdx.x * blockDim.x + threadIdx.x;
    if (p >= P) return;
    float lx = light_dir[0], ly = light_dir[1], lz = light_dir[2];
    float inv = rsqrtf(lx * lx + ly * ly + lz * lz);
    lx *= inv; ly *= inv; lz *= inv;
    float nx = normals[3 * p + 0];
    float ny = normals[3 * p + 1];
    float nz = normals[3 * p + 2];
    float ndl = fabsf(nx * lx + ny * ly + nz * lz);
    float s = AMBIENT + DIFFUSE * ndl;
#pragma unroll
    for (int c = 0; c < 3; ++c) {
        float v = features[3 * p + c] * s;
        shaded[3 * p + c] = fminf(fmaxf(v, 0.0f), 1.0f);
    }
}

// Kernel 2: per-pixel: first depth slot decides everything.
// img = (idx0 >= 0) ? shaded[idx0] : (1,1,1)
__global__ void composite_kernel(const int* __restrict__ idx,
                                 const float* __restrict__ shaded,
                                 float* __restrict__ out,
                                 int num_pixels, int K) {
    int p = blockIdx.x * blockDim.x + threadIdx.x;
    if (p >= num_pixels) return;
    int i0 = idx[(long long)p * K];
    float r, g, b;
    if (i0 >= 0) {
        r = shaded[3 * i0 + 0];
        g = shaded[3 * i0 + 1];
        b = shaded[3 * i0 + 2];
    } else {
        r = 1.0f; g = 1.0f; b = 1.0f;
    }
    out[3 * p + 0] = r;
    out[3 * p + 1] = g;
    out[3 * p + 2] = b;
}

extern "C" void kernel_launch(void* const* d_in, const int* in_sizes, int n_in,
                              void* d_out, int out_size, void* d_ws, size_t ws_size,
                              hipStream_t stream) {
    const int*   idx       = (const int*)d_in[0];
    const float* features  = (const float*)d_in[1];
    const float* normals   = (const float*)d_in[2];
    const float* light_dir = (const float*)d_in[3];
    float*       out       = (float*)d_out;
    float*       shaded    = (float*)d_ws;

    const int P          = in_sizes[1] / 3;          // 100000
    const int num_pixels = out_size / 3;             // N*H*W = 2,097,152
    const int K          = in_sizes[0] / num_pixels; // 10

    {
        int block = 256;
        int grid  = (P + block - 1) / block;
        shade_kernel<<<grid, block, 0, stream>>>(features, normals, light_dir, shaded, P);
    }
    {
        int block = 256;
        int grid  = (num_pixels + block - 1) / block;
        composite_kernel<<<grid, block, 0, stream>>>(idx, shaded, out, num_pixels, K);
    }
}